// Round 23
// baseline (46.628 us; speedup 1.0000x reference)
//
#include <hip/hip_runtime.h>
#include <math.h>

// Problem constants (b=2, cin=256, h=w=64, C=64, qc=60, pd=4, OUT_K=7)
#define NTAP 49

typedef short bf16x8 __attribute__((ext_vector_type(8)));
typedef float f32x4  __attribute__((ext_vector_type(4)));

__device__ __forceinline__ float b2f(ushort u) {
    return __uint_as_float(((unsigned)u) << 16);
}
__device__ __forceinline__ ushort f2b(float f) {
    unsigned u = __float_as_uint(f);
    return (ushort)((u + 0x7FFFu + ((u >> 16) & 1u)) >> 16);
}
__device__ __forceinline__ int iclamp(int x) { return min(max(x, 0), 63); }

#define LOG2E 1.44269504f
#define S2    (0.125f * LOG2E)

// ws byte offsets
#define WTB_OFF 0u           // bf16 [och][kl][c]               401408 B
#define QH_OFF  598016u      // bf16 [b*4096+n][64]            1048576 B
#define KH_OFF  1646592u
#define VH_OFF  2695168u
#define LP_OFF  3743744u     // f32 [ks*2+b][4096], ks<8        262144 B
#define MXQ_OFF 4005888u     // f32 [256]
#define MXK_OFF 4006912u     // f32 [256]

// block-max -> Mhat, deterministic
__device__ __forceinline__ float mh_reduce(const float* __restrict__ MXq,
                                           const float* __restrict__ MXk,
                                           int b, int t, float* sh) {
    if (t < 64) {
        float a = fmaxf(MXq[(b << 7) + t], MXq[(b << 7) + 64 + t]);
        float k = fmaxf(MXk[(b << 7) + t], MXk[(b << 7) + 64 + t]);
        #pragma unroll
        for (int off = 1; off < 64; off <<= 1) {
            a = fmaxf(a, __shfl_xor(a, off, 64));
            k = fmaxf(k, __shfl_xor(k, off, 64));
        }
        if (t == 0) *sh = 0.125f * sqrtf(a) * sqrtf(k) + 1.0f;
    }
    __syncthreads();
    return *sh;
}

// ---------------- K1: QKV projection + norms; inline fp32->hi/lo weight split ----------------
// grid 256 = 2b x 128 pixel-tiles(32). 512 thr = 8 waves. T14 staging per c8.
__global__ __launch_bounds__(512, 2) void k_qkv(
    const float* __restrict__ x,
    const float* __restrict__ Wq, const float* __restrict__ Wk, const float* __restrict__ Wv,
    const float* __restrict__ bq, const float* __restrict__ bk, const float* __restrict__ bv,
    const float* __restrict__ Wp, const float* __restrict__ bp,
    ushort* __restrict__ QKV, float* __restrict__ MXq, float* __restrict__ MXk)
{
    __shared__ ushort Xh[32 * 256];
    __shared__ ushort Xl[32 * 256];
    __shared__ ushort Wshl[192 * 64];    // [och][4 hi granules | 4 lo granules], 24576 B
    __shared__ float  sqL[64];
    int bid0 = blockIdx.x;
    int bid  = (bid0 & 7) * 32 + (bid0 >> 3);   // XCD swizzle (256 = 8 x 32)
    int b   = bid >> 7;
    int n0  = (bid & 127) * 32;
    int t   = threadIdx.x;
    int w    = t >> 6;
    int L    = t & 63;
    int lrow = L & 15, lk = L >> 4;

    if (t < 64) sqL[t] = 0.f;
    {
        int p  = t & 31;
        int cg = t >> 5;
        #pragma unroll
        for (int it = 0; it < 2; ++it) {
            int cgi = cg + it * 16;
            float v[8];
            #pragma unroll
            for (int e = 0; e < 8; ++e)
                v[e] = x[((size_t)(b * 256 + cgi * 8 + e) << 12) + n0 + p];
            bf16x8 hi, lo;
            #pragma unroll
            for (int e = 0; e < 8; ++e) {
                ushort h = f2b(v[e]);
                hi[e] = (short)h;
                lo[e] = (short)f2b(v[e] - b2f(h));
            }
            int off = p * 256 + ((cgi * 8) ^ ((p & 7) * 8));
            *(bf16x8*)(Xh + off) = hi;
            *(bf16x8*)(Xl + off) = lo;
        }
    }

    // per-thread weight staging state: 3 granules, 8 fp32 each
    int   s_och[3], s_g[3];
    bool  s_live[3];
    const float* s_src[3];
    #pragma unroll
    for (int s = 0; s < 3; ++s) {
        int g_idx = t + s * 512;
        int och = g_idx >> 3, g = g_idx & 7;
        int mat = och >> 6, o = och & 63;
        const float* Wm = (mat == 0) ? Wq : (mat == 1) ? Wk : Wv;
        s_och[s] = och; s_g[s] = g;
        s_live[s] = (o < 60);
        s_src[s] = Wm + o * 256 + (g & 3) * 8;
    }
    float4 wreg[3][2];

    #define ISSUE_W(c8) {                                                   \
        _Pragma("unroll")                                                   \
        for (int s = 0; s < 3; ++s) {                                       \
            if (s_live[s]) {                                                \
                const float* sp = s_src[s] + (c8) * 32;                     \
                wreg[s][0] = *(const float4*)(sp);                          \
                wreg[s][1] = *(const float4*)(sp + 4);                      \
            } else {                                                        \
                wreg[s][0] = make_float4(0.f,0.f,0.f,0.f);                  \
                wreg[s][1] = make_float4(0.f,0.f,0.f,0.f);                  \
            }                                                               \
        } }
    #define WRITE_W() {                                                     \
        _Pragma("unroll")                                                   \
        for (int s = 0; s < 3; ++s) {                                       \
            float vv[8] = {wreg[s][0].x, wreg[s][0].y, wreg[s][0].z,        \
                           wreg[s][0].w, wreg[s][1].x, wreg[s][1].y,        \
                           wreg[s][1].z, wreg[s][1].w};                     \
            bf16x8 val;                                                     \
            _Pragma("unroll")                                               \
            for (int e = 0; e < 8; ++e) {                                   \
                ushort h = f2b(vv[e]);                                      \
                val[e] = (s_g[s] < 4) ? (short)h                            \
                                      : (short)f2b(vv[e] - b2f(h));         \
            }                                                               \
            *(bf16x8*)((char*)Wshl + s_och[s] * 128 +                       \
                       ((s_g[s] * 16) ^ ((s_och[s] & 7) << 4))) = val;      \
        } }

    ISSUE_W(0);
    __syncthreads();                     // X writes visible
    WRITE_W();
    __syncthreads();                     // Wshl[c8=0] ready

    int pxh = w >> 2;
    int ob  = (w & 3) * 48;
    int px  = pxh * 16 + lrow;

    f32x4 acc[3] = {{0,0,0,0},{0,0,0,0},{0,0,0,0}};

    for (int c8 = 0; c8 < 8; ++c8) {
        if (c8 + 1 < 8) ISSUE_W(c8 + 1);
        int cidx = (c8 * 4 + lk) * 8;
        int o0 = px * 256 + (cidx ^ ((px & 7) * 8));
        bf16x8 ah = *(const bf16x8*)(Xh + o0);
        bf16x8 al = *(const bf16x8*)(Xl + o0);
        __builtin_amdgcn_s_setprio(1);
        #pragma unroll
        for (int c = 0; c < 3; ++c) {
            int och = ob + c * 16 + lrow;
            const char* wb = (const char*)Wshl + och * 128;
            int swz = (och & 7) << 4;
            bf16x8 bh = *(const bf16x8*)(wb + ((lk * 16) ^ swz));
            bf16x8 bl = *(const bf16x8*)(wb + (((4 + lk) * 16) ^ swz));
            acc[c] = __builtin_amdgcn_mfma_f32_16x16x32_bf16(al, bh, acc[c], 0, 0, 0);
            acc[c] = __builtin_amdgcn_mfma_f32_16x16x32_bf16(ah, bl, acc[c], 0, 0, 0);
            acc[c] = __builtin_amdgcn_mfma_f32_16x16x32_bf16(ah, bh, acc[c], 0, 0, 0);
        }
        __builtin_amdgcn_s_setprio(0);
        __syncthreads();
        if (c8 + 1 < 8) WRITE_W();
        __syncthreads();
    }

    float s_q[4] = {0,0,0,0}, s_k[4] = {0,0,0,0};
    #pragma unroll
    for (int c = 0; c < 3; ++c) {
        int och = ob + c * 16 + lrow;
        int mat = och >> 6;
        int o   = och & 63;
        const float* bm = (mat == 0) ? bq : (mat == 1) ? bk : bv;
        ushort* Ob = QKV + (size_t)mat * 524288;
        if (o < 60) {
            float bias = bm[o];
            #pragma unroll
            for (int e = 0; e < 4; ++e) {
                int n = n0 + pxh * 16 + lk * 4 + e;
                float v = acc[c][e] + bias;
                Ob[((size_t)((b << 12) + n)) * 64 + o] = f2b(v);
                if (mat == 0) s_q[e] = fmaf(v, v, s_q[e]);
                else if (mat == 1) s_k[e] = fmaf(v, v, s_k[e]);
            }
        } else {
            int po = o - 60;
            float w0 = Wp[2 * po], w1 = Wp[2 * po + 1], b0 = bp[po];
            #pragma unroll
            for (int e = 0; e < 4; ++e) {
                int n = n0 + pxh * 16 + lk * 4 + e;
                float fi = (float)(n >> 6), fj = (float)(n & 63);
                float pv = fmaf(w0, fi, fmaf(w1, fj, b0));
                Ob[((size_t)((b << 12) + n)) * 64 + o] = f2b(pv);
                if (mat == 0) s_q[e] = fmaf(pv, pv, s_q[e]);
                else if (mat == 1) s_k[e] = fmaf(pv, pv, s_k[e]);
            }
        }
    }
    #pragma unroll
    for (int off = 1; off < 16; off <<= 1) {
        #pragma unroll
        for (int e = 0; e < 4; ++e) {
            s_q[e] += __shfl_xor(s_q[e], off, 64);
            s_k[e] += __shfl_xor(s_k[e], off, 64);
        }
    }
    if (lrow == 0) {
        #pragma unroll
        for (int e = 0; e < 4; ++e) {
            int pix = pxh * 16 + lk * 4 + e;
            atomicAdd(&sqL[pix],      s_q[e]);
            atomicAdd(&sqL[32 + pix], s_k[e]);
        }
    }
    __syncthreads();
    if (t < 32) {
        float q2 = sqL[t], k2 = sqL[32 + t];
        #pragma unroll
        for (int off = 1; off < 32; off <<= 1) {
            q2 = fmaxf(q2, __shfl_xor(q2, off, 64));
            k2 = fmaxf(k2, __shfl_xor(k2, off, 64));
        }
        if (t == 0) { MXq[bid] = q2; MXk[bid] = k2; }
    }
}

// ---------------- K2: Wtb transpose + softmax denominator partials ----------------
// grid 512 = 8 ks(512 keys) x 2b x 32 rowtiles(128). 512 thr = 8 waves.
__global__ __launch_bounds__(512, 2) void k_stats(
    const float* __restrict__ Wout, ushort* __restrict__ Wtb,
    const ushort* __restrict__ QH, const ushort* __restrict__ KH,
    const float* __restrict__ MXq, const float* __restrict__ MXk,
    float* __restrict__ Lp)
{
    __shared__ ushort Ks[2][128 * 64];
    __shared__ float  mhs;
    int bid0 = blockIdx.x;
    int bid  = (bid0 & 7) * 64 + (bid0 >> 3);   // XCD swizzle (512 = 8 x 64)
    int ks  = bid & 7;
    int r   = bid >> 3;
    int b   = r >> 5;
    int n0  = (r & 31) * 128;
    int ck0 = ks * 512;
    int t = threadIdx.x;
    int w = t >> 6, L = t & 63;
    int lrow = L & 15, lk = L >> 4;

    // hoisted A-frag loads: latency hides under Wtb prep + mh_reduce
    size_t qbase = ((size_t)((b << 12) + n0 + w * 16 + lrow)) * 64 + lk * 8;
    bf16x8 a0 = *(const bf16x8*)(QH + qbase);
    bf16x8 a1 = *(const bf16x8*)(QH + qbase + 32);

    // folded prep: Wout (o,c,kl) -> Wtb [och][kl][c], one elem/thread
    {
        int widx = bid * 512 + t;
        if (widx < 64 * 64 * NTAP) {
            int o   = widx / (64 * NTAP);
            int rem = widx - o * (64 * NTAP);
            int c   = rem / NTAP;
            int kl  = rem - c * NTAP;
            Wtb[(o * NTAP + kl) * 64 + c] = f2b(Wout[widx]);
        }
    }
    float bse = -mh_reduce(MXq, MXk, b, t, &mhs) * LOG2E;

    #pragma unroll
    for (int gi = 0; gi < 2; ++gi) {
        int g = t + gi * 512;
        int u = g >> 3, c8 = g & 7;
        bf16x8 val = *(const bf16x8*)(KH + ((size_t)((b << 12) + ck0 + u)) * 64 + c8 * 8);
        *(bf16x8*)((char*)Ks[0] + u * 128 + ((c8 * 16) ^ ((u & 7) << 4))) = val;
    }

    float rs0 = 0.f, rs1 = 0.f, rs2 = 0.f, rs3 = 0.f;

    for (int c = 0; c < 4; ++c) {
        bf16x8 st0, st1;
        int u0 = t >> 3, c80 = t & 7;
        int u1 = (t + 512) >> 3, c81 = t & 7;
        bool pf = (c + 1) < 4;
        if (pf) {
            st0 = *(const bf16x8*)(KH + ((size_t)((b << 12) + ck0 + (c + 1) * 128 + u0)) * 64 + c80 * 8);
            st1 = *(const bf16x8*)(KH + ((size_t)((b << 12) + ck0 + (c + 1) * 128 + u1)) * 64 + c81 * 8);
        }
        __syncthreads();
        const char* kb = (const char*)Ks[c & 1];
        __builtin_amdgcn_s_setprio(1);
        #pragma unroll
        for (int kg = 0; kg < 8; ++kg) {
            int u = kg * 16 + lrow;
            int swz = (u & 7) << 4;
            bf16x8 b0 = *(const bf16x8*)(kb + u * 128 + ((lk * 16) ^ swz));
            bf16x8 b1 = *(const bf16x8*)(kb + u * 128 + ((64 + lk * 16) ^ swz));
            f32x4 z = {0.f, 0.f, 0.f, 0.f};
            z = __builtin_amdgcn_mfma_f32_16x16x32_bf16(a0, b0, z, 0, 0, 0);
            z = __builtin_amdgcn_mfma_f32_16x16x32_bf16(a1, b1, z, 0, 0, 0);
            rs0 += exp2f(fmaf(z[0], S2, bse));
            rs1 += exp2f(fmaf(z[1], S2, bse));
            rs2 += exp2f(fmaf(z[2], S2, bse));
            rs3 += exp2f(fmaf(z[3], S2, bse));
        }
        __builtin_amdgcn_s_setprio(0);
        if (pf) {
            char* kn = (char*)Ks[(c + 1) & 1];
            *(bf16x8*)(kn + u0 * 128 + ((c80 * 16) ^ ((u0 & 7) << 4))) = st0;
            *(bf16x8*)(kn + u1 * 128 + ((c81 * 16) ^ ((u1 & 7) << 4))) = st1;
        }
    }
    #pragma unroll
    for (int off = 1; off < 16; off <<= 1) {
        rs0 += __shfl_xor(rs0, off, 64);
        rs1 += __shfl_xor(rs1, off, 64);
        rs2 += __shfl_xor(rs2, off, 64);
        rs3 += __shfl_xor(rs3, off, 64);
    }
    if (lrow == 0) {
        float* dst = Lp + ((size_t)(ks * 2 + b) << 12) + n0 + w * 16 + lk * 4;
        dst[0] = rs0; dst[1] = rs1; dst[2] = rs2; dst[3] = rs3;
    }
}

// ---------------- K3: local attn + output conv; double-buffered Ws (1 barrier/kk) ----------------
// grid 256 = 2b x 64 rows x 2 col-halves (32 px). 512 thr = 8 waves.
// LDS: Vs | Ws0 | Ws1 (Kh aliases Ws1's first 35840 B; Kh dead after phase A).
#define SM_VS   0
#define SM_WS0  35840
#define SM_WS1  93184
#define SM_KHA  93184
#define SM_AL2  150528
#define SM_LROW 157584
#define SM_LCS  157712
#define SM_MHS  157840
__global__ __launch_bounds__(512, 1) void k_out(
    const ushort* __restrict__ QH, const ushort* __restrict__ KH,
    const ushort* __restrict__ VH, const ushort* __restrict__ Wtb,
    const float* __restrict__ Lp,
    const float* __restrict__ MXq, const float* __restrict__ MXk,
    const float* __restrict__ bout, float* __restrict__ out)
{
    __shared__ __align__(16) char smem[157856];
    char*  Vsb  = smem + SM_VS;
    char*  Khb  = smem + SM_KHA;
    float* Al2  = (float*)(smem + SM_AL2);
    float* Lrow = (float*)(smem + SM_LROW);
    float* LcS  = (float*)(smem + SM_LCS);

    int bid0 = blockIdx.x;
    int bid  = (bid0 & 7) * 32 + (bid0 >> 3);   // XCD swizzle (256 = 8 x 32)
    int b   = bid >> 7;
    int rem = bid & 127;
    int i   = rem >> 1;
    int j0  = (rem & 1) * 32;
    int n0  = (i << 6) + j0;
    int t   = threadIdx.x;
    int w    = t >> 6;
    int L    = t & 63;
    int lrow = L & 15, lk = L >> 4;

    // T14 state for Ws staging
    bf16x8 wreg[7];
    #define ISSUE_WS(kk) {                                                          \
        _Pragma("unroll")                                                           \
        for (int s = 0; s < 7; ++s) {                                               \
            int g = t + s * 512;                                                    \
            int c8 = g & 7, och = (g >> 3) & 63, ll = g >> 9;                       \
            wreg[s] = *(const bf16x8*)(Wtb + ((size_t)(och * NTAP + (kk) * 7 + ll)) * 64 + c8 * 8); \
        } }
    #define WRITE_WS(dstb) {                                                        \
        _Pragma("unroll")                                                           \
        for (int s = 0; s < 7; ++s) {                                               \
            int g = t + s * 512;                                                    \
            int c8 = g & 7, och = (g >> 3) & 63, ll = g >> 9;                       \
            *(bf16x8*)((dstb) + ll * 8192 + och * 128 +                             \
                       ((c8 * 16) ^ ((och & 7) << 4))) = wreg[s];                   \
        } }

    // ---- hoisted loads: Ws slice 0 + phase-A Q rows (latency hides under staging) ----
    ISSUE_WS(0);
    int pA = t >> 4, uA = t & 15;
    int nA = n0 + pA;
    bf16x8 qv[8];
    {
        const ushort* qr = QH + ((size_t)(b << 12) + nA) * 64;
        #pragma unroll
        for (int c8 = 0; c8 < 8; ++c8) qv[c8] = *(const bf16x8*)(qr + c8 * 8);
    }
    float bse = -mh_reduce(MXq, MXk, b, t, (float*)(smem + SM_MHS)) * LOG2E;
    float e0  = exp2f(bse);

    // ---- stage V + K halos ----
    for (int g = t; g < 2 * 7 * 38 * 8; g += 512) {
        int which = g >= 7 * 38 * 8;
        int gg = which ? g - 7 * 38 * 8 : g;
        int kk = gg / 304;
        int r2 = gg - kk * 304;
        int u  = r2 >> 3, c8 = r2 & 7;
        int vr = iclamp(i + kk - 3);
        int vc = iclamp(j0 - 3 + u);
        const ushort* src = which ? KH : VH;
        char* dst = which ? Khb : Vsb;
        bf16x8 val = *(const bf16x8*)(src + ((size_t)((b << 12) + (vr << 6) + vc)) * 64 + c8 * 8);
        *(bf16x8*)(dst + kk * 5120 + u * 128 + ((c8 * 16) ^ ((u & 7) << 4))) = val;
    }
    WRITE_WS(smem + SM_WS0);
    if (t < 32) {
        int n = n0 + t;
        float s = 0.f;
        #pragma unroll
        for (int ks = 0; ks < 8; ++ks)
            s += Lp[((size_t)(ks * 2 + b) << 12) + n];
        Lrow[t] = s;
    }
    __syncthreads();

    // ---- phase A: local dots from LDS K-halo (32 px x 16 thr) ----
    {
        int p = pA, u = uA;
        int n = nA;
        int pj = n & 63;

        int nt = (u == 0) ? 4 : 3;
        float d[4] = {0.f, 0.f, 0.f, 0.f};
        int srcs[4];
        const char* kbp[4];
        int swzs[4];
        #pragma unroll
        for (int m = 0; m < 4; ++m) {
            int tap = (m == 3) ? 48 : (u + 16 * m);
            int kk = tap / 7, ll = tap - kk * 7;
            srcs[m] = (iclamp(i + kk - 3) << 6) + iclamp(pj + ll - 3);
            int uu = p + ll;
            kbp[m]  = Khb + kk * 5120 + uu * 128;
            swzs[m] = (uu & 7) << 4;
        }
        #pragma unroll
        for (int c8 = 0; c8 < 8; ++c8) {
            bf16x8 kv0 = *(const bf16x8*)(kbp[0] + ((c8 * 16) ^ swzs[0]));
            bf16x8 kv1 = *(const bf16x8*)(kbp[1] + ((c8 * 16) ^ swzs[1]));
            bf16x8 kv2 = *(const bf16x8*)(kbp[2] + ((c8 * 16) ^ swzs[2]));
            #pragma unroll
            for (int e = 0; e < 8; ++e) {
                float q = b2f((ushort)qv[c8][e]);
                d[0] = fmaf(q, b2f((ushort)kv0[e]), d[0]);
                d[1] = fmaf(q, b2f((ushort)kv1[e]), d[1]);
                d[2] = fmaf(q, b2f((ushort)kv2[e]), d[2]);
            }
        }
        if (nt == 4) {
            #pragma unroll
            for (int c8 = 0; c8 < 8; ++c8) {
                bf16x8 kv3 = *(const bf16x8*)(kbp[3] + ((c8 * 16) ^ swzs[3]));
                #pragma unroll
                for (int e = 0; e < 8; ++e)
                    d[3] = fmaf(b2f((ushort)qv[c8][e]), b2f((ushort)kv3[e]), d[3]);
            }
        }
        if (u == 8)                       // tap 24 = center (src == n always)
            LcS[p] = Lrow[p] - exp2f(fmaf(d[1], S2, bse)) + e0;
        __syncthreads();
        float rLc = 1.0f / LcS[p];
        for (int m = 0; m < nt; ++m) {
            int tap = (m == 3) ? 48 : (u + 16 * m);
            float A = (srcs[m] == n) ? (e0 * rLc)
                                     : (exp2f(fmaf(d[m], S2, bse)) * rLc);
            Al2[tap * 36 + p] = A;
        }
    }
    __syncthreads();                     // Al2 + Ws0 ready; Kh reads done

    // ---- phase B: per-tap MFMA, scale-after; double-buffered Ws, 1 barrier/kk ----
    int q16 = (w >> 2) << 4;
    int o16 = (w & 3) << 4;
    int oA  = o16 + lrow;
    int wswz = (oA & 7) << 4;
    f32x4 acc0 = {0.f, 0.f, 0.f, 0.f};

    for (int kk = 0; kk < 7; ++kk) {
        if (kk + 1 < 7) ISSUE_WS(kk + 1);
        const char* vrow = Vsb + kk * 5120;
        const char* wsb  = smem + ((kk & 1) ? SM_WS1 : SM_WS0);
        __builtin_amdgcn_s_setprio(1);
        #pragma unroll
        for (int ll = 0; ll < 7; ++ll) {
            int kl = kk * 7 + ll;
            int u = q16 + lrow + ll;
            const char* vb = vrow + u * 128;
            int swz = (u & 7) << 4;
            bf16x8 v0 = *(const bf16x8*)(vb + ((lk * 16) ^ swz));
            bf16x8 v1 = *(const bf16x8*)(vb + ((64 + lk * 16) ^ swz));
            float4 av = *(const float4*)(&Al2[kl * 36 + q16 + lk * 4]);
            const char* wb = wsb + ll * 8192 + oA * 128;
            bf16x8 b00 = *(const bf16x8*)(wb + ((lk * 16) ^ wswz));
            bf16x8 b01 = *(const bf16x8*)(wb + (((4 + lk) * 16) ^ wswz));
            f32x4 z = {0.f, 0.f, 0.f, 0.f};
            z = __builtin_amdgcn_mfma_f32_16x16x32_bf16(v0, b00, z, 0, 0, 0);
            z = __builtin_amdgcn_mfma_f32_16x16x32_bf16(v1, b01, z, 0, 0, 0);
            acc0[0] = fmaf(av.x, z[0], acc0[0]);
            acc0[1] = fmaf(av.y, z[1], acc0[1]);
            acc0[2] = fmaf(av.z, z[2], acc0[2]);
            acc0[3] = fmaf(av.w, z[3], acc0[3]);
        }
        __builtin_amdgcn_s_setprio(0);
        if (kk + 1 < 7) WRITE_WS(smem + (((kk + 1) & 1) ? SM_WS1 : SM_WS0));
        __syncthreads();                 // write(kk)->read(kk+1) AND read(kk)->write(kk+1)
    }

    int o = oA;
    int nbase = n0 + q16 + lk * 4;
    float bb = bout[o];
    float4 v = make_float4(fmaxf(acc0[0] + bb, 0.f), fmaxf(acc0[1] + bb, 0.f),
                           fmaxf(acc0[2] + bb, 0.f), fmaxf(acc0[3] + bb, 0.f));
    *(float4*)(out + (((size_t)(b * 64 + o)) << 12) + nbase) = v;
}

// ---------------- launch ----------------
extern "C" void kernel_launch(void* const* d_in, const int* in_sizes, int n_in,
                              void* d_out, int out_size, void* d_ws, size_t ws_size,
                              hipStream_t stream) {
    const float* x    = (const float*)d_in[0];
    const float* Wq   = (const float*)d_in[1];
    const float* bq   = (const float*)d_in[2];
    const float* Wk   = (const float*)d_in[3];
    const float* bk   = (const float*)d_in[4];
    const float* Wv   = (const float*)d_in[5];
    const float* bv   = (const float*)d_in[6];
    const float* Wp   = (const float*)d_in[7];
    const float* bp   = (const float*)d_in[8];
    const float* Wout = (const float*)d_in[9];
    const float* bout = (const float*)d_in[10];
    float* out = (float*)d_out;

    char* ws = (char*)d_ws;
    ushort* Wtb = (ushort*)(ws + WTB_OFF);
    ushort* QKV = (ushort*)(ws + QH_OFF);
    float*  Lp  = (float*)(ws + LP_OFF);
    float*  MXq = (float*)(ws + MXQ_OFF);
    float*  MXk = (float*)(ws + MXK_OFF);

    ushort* QH = QKV;
    ushort* KH = QKV + 524288;
    ushort* VH = QKV + 1048576;

    hipLaunchKernelGGL(k_qkv,   dim3(256), dim3(512), 0, stream,
                       x, Wq, Wk, Wv, bq, bk, bv, Wp, bp, QKV, MXq, MXk);
    hipLaunchKernelGGL(k_stats, dim3(512), dim3(512), 0, stream,
                       Wout, Wtb, QH, KH, MXq, MXk, Lp);
    hipLaunchKernelGGL(k_out,   dim3(256), dim3(512), 0, stream,
                       QH, KH, VH, Wtb, Lp, MXq, MXk, bout, out);
}

// Round 24
// 45.299 us; speedup vs baseline: 1.0293x; 1.0293x over previous
//
#include <hip/hip_runtime.h>
#include <math.h>

// Problem constants (b=2, cin=256, h=w=64, C=64, qc=60, pd=4, OUT_K=7)
#define NTAP 49

typedef short bf16x8 __attribute__((ext_vector_type(8)));
typedef float f32x4  __attribute__((ext_vector_type(4)));

__device__ __forceinline__ float b2f(ushort u) {
    return __uint_as_float(((unsigned)u) << 16);
}
__device__ __forceinline__ ushort f2b(float f) {
    unsigned u = __float_as_uint(f);
    return (ushort)((u + 0x7FFFu + ((u >> 16) & 1u)) >> 16);
}
__device__ __forceinline__ int iclamp(int x) { return min(max(x, 0), 63); }

#define LOG2E 1.44269504f
#define S2    (0.125f * LOG2E)

// ws byte offsets
#define WTB_OFF 0u           // bf16 [och][kl][c]               401408 B
#define QH_OFF  598016u      // bf16 [b*4096+n][64]            1048576 B
#define KH_OFF  1646592u
#define VH_OFF  2695168u
#define LP_OFF  3743744u     // f32 [ks*2+b][4096], ks<8        262144 B
#define MXQ_OFF 4005888u     // f32 [256]
#define MXK_OFF 4006912u     // f32 [256]

// block-max -> Mhat, deterministic
__device__ __forceinline__ float mh_reduce(const float* __restrict__ MXq,
                                           const float* __restrict__ MXk,
                                           int b, int t, float* sh) {
    if (t < 64) {
        float a = fmaxf(MXq[(b << 7) + t], MXq[(b << 7) + 64 + t]);
        float k = fmaxf(MXk[(b << 7) + t], MXk[(b << 7) + 64 + t]);
        #pragma unroll
        for (int off = 1; off < 64; off <<= 1) {
            a = fmaxf(a, __shfl_xor(a, off, 64));
            k = fmaxf(k, __shfl_xor(k, off, 64));
        }
        if (t == 0) *sh = 0.125f * sqrtf(a) * sqrtf(k) + 1.0f;
    }
    __syncthreads();
    return *sh;
}

// ---------------- K1: QKV projection + norms; inline fp32->hi/lo weight split ----------------
// grid 256 = 2b x 128 pixel-tiles(32). 512 thr = 8 waves. T14 staging per c8.
__global__ __launch_bounds__(512, 2) void k_qkv(
    const float* __restrict__ x,
    const float* __restrict__ Wq, const float* __restrict__ Wk, const float* __restrict__ Wv,
    const float* __restrict__ bq, const float* __restrict__ bk, const float* __restrict__ bv,
    const float* __restrict__ Wp, const float* __restrict__ bp,
    ushort* __restrict__ QKV, float* __restrict__ MXq, float* __restrict__ MXk)
{
    __shared__ ushort Xh[32 * 256];
    __shared__ ushort Xl[32 * 256];
    __shared__ ushort Wshl[192 * 64];    // [och][4 hi granules | 4 lo granules], 24576 B
    __shared__ float  sqL[64];
    int bid0 = blockIdx.x;
    int bid  = (bid0 & 7) * 32 + (bid0 >> 3);   // XCD swizzle (256 = 8 x 32)
    int b   = bid >> 7;
    int n0  = (bid & 127) * 32;
    int t   = threadIdx.x;
    int w    = t >> 6;
    int L    = t & 63;
    int lrow = L & 15, lk = L >> 4;

    if (t < 64) sqL[t] = 0.f;
    {
        int p  = t & 31;
        int cg = t >> 5;
        #pragma unroll
        for (int it = 0; it < 2; ++it) {
            int cgi = cg + it * 16;
            float v[8];
            #pragma unroll
            for (int e = 0; e < 8; ++e)
                v[e] = x[((size_t)(b * 256 + cgi * 8 + e) << 12) + n0 + p];
            bf16x8 hi, lo;
            #pragma unroll
            for (int e = 0; e < 8; ++e) {
                ushort h = f2b(v[e]);
                hi[e] = (short)h;
                lo[e] = (short)f2b(v[e] - b2f(h));
            }
            int off = p * 256 + ((cgi * 8) ^ ((p & 7) * 8));
            *(bf16x8*)(Xh + off) = hi;
            *(bf16x8*)(Xl + off) = lo;
        }
    }

    // per-thread weight staging state: 3 granules, 8 fp32 each
    int   s_och[3], s_g[3];
    bool  s_live[3];
    const float* s_src[3];
    #pragma unroll
    for (int s = 0; s < 3; ++s) {
        int g_idx = t + s * 512;
        int och = g_idx >> 3, g = g_idx & 7;
        int mat = och >> 6, o = och & 63;
        const float* Wm = (mat == 0) ? Wq : (mat == 1) ? Wk : Wv;
        s_och[s] = och; s_g[s] = g;
        s_live[s] = (o < 60);
        s_src[s] = Wm + o * 256 + (g & 3) * 8;
    }
    float4 wreg[3][2];

    #define ISSUE_W(c8) {                                                   \
        _Pragma("unroll")                                                   \
        for (int s = 0; s < 3; ++s) {                                       \
            if (s_live[s]) {                                                \
                const float* sp = s_src[s] + (c8) * 32;                     \
                wreg[s][0] = *(const float4*)(sp);                          \
                wreg[s][1] = *(const float4*)(sp + 4);                      \
            } else {                                                        \
                wreg[s][0] = make_float4(0.f,0.f,0.f,0.f);                  \
                wreg[s][1] = make_float4(0.f,0.f,0.f,0.f);                  \
            }                                                               \
        } }
    #define WRITE_W() {                                                     \
        _Pragma("unroll")                                                   \
        for (int s = 0; s < 3; ++s) {                                       \
            float vv[8] = {wreg[s][0].x, wreg[s][0].y, wreg[s][0].z,        \
                           wreg[s][0].w, wreg[s][1].x, wreg[s][1].y,        \
                           wreg[s][1].z, wreg[s][1].w};                     \
            bf16x8 val;                                                     \
            _Pragma("unroll")                                               \
            for (int e = 0; e < 8; ++e) {                                   \
                ushort h = f2b(vv[e]);                                      \
                val[e] = (s_g[s] < 4) ? (short)h                            \
                                      : (short)f2b(vv[e] - b2f(h));         \
            }                                                               \
            *(bf16x8*)((char*)Wshl + s_och[s] * 128 +                       \
                       ((s_g[s] * 16) ^ ((s_och[s] & 7) << 4))) = val;      \
        } }

    ISSUE_W(0);
    __syncthreads();                     // X writes visible
    WRITE_W();
    __syncthreads();                     // Wshl[c8=0] ready

    int pxh = w >> 2;
    int ob  = (w & 3) * 48;
    int px  = pxh * 16 + lrow;

    f32x4 acc[3] = {{0,0,0,0},{0,0,0,0},{0,0,0,0}};

    for (int c8 = 0; c8 < 8; ++c8) {
        if (c8 + 1 < 8) ISSUE_W(c8 + 1);
        int cidx = (c8 * 4 + lk) * 8;
        int o0 = px * 256 + (cidx ^ ((px & 7) * 8));
        bf16x8 ah = *(const bf16x8*)(Xh + o0);
        bf16x8 al = *(const bf16x8*)(Xl + o0);
        __builtin_amdgcn_s_setprio(1);
        #pragma unroll
        for (int c = 0; c < 3; ++c) {
            int och = ob + c * 16 + lrow;
            const char* wb = (const char*)Wshl + och * 128;
            int swz = (och & 7) << 4;
            bf16x8 bh = *(const bf16x8*)(wb + ((lk * 16) ^ swz));
            bf16x8 bl = *(const bf16x8*)(wb + (((4 + lk) * 16) ^ swz));
            acc[c] = __builtin_amdgcn_mfma_f32_16x16x32_bf16(al, bh, acc[c], 0, 0, 0);
            acc[c] = __builtin_amdgcn_mfma_f32_16x16x32_bf16(ah, bl, acc[c], 0, 0, 0);
            acc[c] = __builtin_amdgcn_mfma_f32_16x16x32_bf16(ah, bh, acc[c], 0, 0, 0);
        }
        __builtin_amdgcn_s_setprio(0);
        __syncthreads();
        if (c8 + 1 < 8) WRITE_W();
        __syncthreads();
    }

    float s_q[4] = {0,0,0,0}, s_k[4] = {0,0,0,0};
    #pragma unroll
    for (int c = 0; c < 3; ++c) {
        int och = ob + c * 16 + lrow;
        int mat = och >> 6;
        int o   = och & 63;
        const float* bm = (mat == 0) ? bq : (mat == 1) ? bk : bv;
        ushort* Ob = QKV + (size_t)mat * 524288;
        if (o < 60) {
            float bias = bm[o];
            #pragma unroll
            for (int e = 0; e < 4; ++e) {
                int n = n0 + pxh * 16 + lk * 4 + e;
                float v = acc[c][e] + bias;
                Ob[((size_t)((b << 12) + n)) * 64 + o] = f2b(v);
                if (mat == 0) s_q[e] = fmaf(v, v, s_q[e]);
                else if (mat == 1) s_k[e] = fmaf(v, v, s_k[e]);
            }
        } else {
            int po = o - 60;
            float w0 = Wp[2 * po], w1 = Wp[2 * po + 1], b0 = bp[po];
            #pragma unroll
            for (int e = 0; e < 4; ++e) {
                int n = n0 + pxh * 16 + lk * 4 + e;
                float fi = (float)(n >> 6), fj = (float)(n & 63);
                float pv = fmaf(w0, fi, fmaf(w1, fj, b0));
                Ob[((size_t)((b << 12) + n)) * 64 + o] = f2b(pv);
                if (mat == 0) s_q[e] = fmaf(pv, pv, s_q[e]);
                else if (mat == 1) s_k[e] = fmaf(pv, pv, s_k[e]);
            }
        }
    }
    #pragma unroll
    for (int off = 1; off < 16; off <<= 1) {
        #pragma unroll
        for (int e = 0; e < 4; ++e) {
            s_q[e] += __shfl_xor(s_q[e], off, 64);
            s_k[e] += __shfl_xor(s_k[e], off, 64);
        }
    }
    if (lrow == 0) {
        #pragma unroll
        for (int e = 0; e < 4; ++e) {
            int pix = pxh * 16 + lk * 4 + e;
            atomicAdd(&sqL[pix],      s_q[e]);
            atomicAdd(&sqL[32 + pix], s_k[e]);
        }
    }
    __syncthreads();
    if (t < 32) {
        float q2 = sqL[t], k2 = sqL[32 + t];
        #pragma unroll
        for (int off = 1; off < 32; off <<= 1) {
            q2 = fmaxf(q2, __shfl_xor(q2, off, 64));
            k2 = fmaxf(k2, __shfl_xor(k2, off, 64));
        }
        if (t == 0) { MXq[bid] = q2; MXk[bid] = k2; }
    }
}

// ---------------- K2: Wtb transpose + softmax denominator partials ----------------
// grid 512 = 8 ks(512 keys) x 2b x 32 rowtiles(128). 512 thr = 8 waves.
__global__ __launch_bounds__(512, 2) void k_stats(
    const float* __restrict__ Wout, ushort* __restrict__ Wtb,
    const ushort* __restrict__ QH, const ushort* __restrict__ KH,
    const float* __restrict__ MXq, const float* __restrict__ MXk,
    float* __restrict__ Lp)
{
    __shared__ ushort Ks[2][128 * 64];
    __shared__ float  mhs;
    int bid0 = blockIdx.x;
    int bid  = (bid0 & 7) * 64 + (bid0 >> 3);   // XCD swizzle (512 = 8 x 64)
    int ks  = bid & 7;
    int r   = bid >> 3;
    int b   = r >> 5;
    int n0  = (r & 31) * 128;
    int ck0 = ks * 512;
    int t = threadIdx.x;

    // folded prep: Wout (o,c,kl) -> Wtb [och][kl][c], one elem/thread
    {
        int widx = bid * 512 + t;
        if (widx < 64 * 64 * NTAP) {
            int o   = widx / (64 * NTAP);
            int rem = widx - o * (64 * NTAP);
            int c   = rem / NTAP;
            int kl  = rem - c * NTAP;
            Wtb[(o * NTAP + kl) * 64 + c] = f2b(Wout[widx]);
        }
    }
    float bse = -mh_reduce(MXq, MXk, b, t, &mhs) * LOG2E;

    int w = t >> 6, L = t & 63;
    int lrow = L & 15, lk = L >> 4;

    size_t qbase = ((size_t)((b << 12) + n0 + w * 16 + lrow)) * 64 + lk * 8;
    bf16x8 a0 = *(const bf16x8*)(QH + qbase);
    bf16x8 a1 = *(const bf16x8*)(QH + qbase + 32);

    #pragma unroll
    for (int gi = 0; gi < 2; ++gi) {
        int g = t + gi * 512;
        int u = g >> 3, c8 = g & 7;
        bf16x8 val = *(const bf16x8*)(KH + ((size_t)((b << 12) + ck0 + u)) * 64 + c8 * 8);
        *(bf16x8*)((char*)Ks[0] + u * 128 + ((c8 * 16) ^ ((u & 7) << 4))) = val;
    }

    float rs0 = 0.f, rs1 = 0.f, rs2 = 0.f, rs3 = 0.f;

    for (int c = 0; c < 4; ++c) {
        bf16x8 st0, st1;
        int u0 = t >> 3, c80 = t & 7;
        int u1 = (t + 512) >> 3, c81 = t & 7;
        bool pf = (c + 1) < 4;
        if (pf) {
            st0 = *(const bf16x8*)(KH + ((size_t)((b << 12) + ck0 + (c + 1) * 128 + u0)) * 64 + c80 * 8);
            st1 = *(const bf16x8*)(KH + ((size_t)((b << 12) + ck0 + (c + 1) * 128 + u1)) * 64 + c81 * 8);
        }
        __syncthreads();
        const char* kb = (const char*)Ks[c & 1];
        __builtin_amdgcn_s_setprio(1);
        #pragma unroll
        for (int kg = 0; kg < 8; ++kg) {
            int u = kg * 16 + lrow;
            int swz = (u & 7) << 4;
            bf16x8 b0 = *(const bf16x8*)(kb + u * 128 + ((lk * 16) ^ swz));
            bf16x8 b1 = *(const bf16x8*)(kb + u * 128 + ((64 + lk * 16) ^ swz));
            f32x4 z = {0.f, 0.f, 0.f, 0.f};
            z = __builtin_amdgcn_mfma_f32_16x16x32_bf16(a0, b0, z, 0, 0, 0);
            z = __builtin_amdgcn_mfma_f32_16x16x32_bf16(a1, b1, z, 0, 0, 0);
            rs0 += exp2f(fmaf(z[0], S2, bse));
            rs1 += exp2f(fmaf(z[1], S2, bse));
            rs2 += exp2f(fmaf(z[2], S2, bse));
            rs3 += exp2f(fmaf(z[3], S2, bse));
        }
        __builtin_amdgcn_s_setprio(0);
        if (pf) {
            char* kn = (char*)Ks[(c + 1) & 1];
            *(bf16x8*)(kn + u0 * 128 + ((c80 * 16) ^ ((u0 & 7) << 4))) = st0;
            *(bf16x8*)(kn + u1 * 128 + ((c81 * 16) ^ ((u1 & 7) << 4))) = st1;
        }
    }
    #pragma unroll
    for (int off = 1; off < 16; off <<= 1) {
        rs0 += __shfl_xor(rs0, off, 64);
        rs1 += __shfl_xor(rs1, off, 64);
        rs2 += __shfl_xor(rs2, off, 64);
        rs3 += __shfl_xor(rs3, off, 64);
    }
    if (lrow == 0) {
        float* dst = Lp + ((size_t)(ks * 2 + b) << 12) + n0 + w * 16 + lk * 4;
        dst[0] = rs0; dst[1] = rs1; dst[2] = rs2; dst[3] = rs3;
    }
}

// ---------------- K3: local attn + output conv; double-buffered Ws (1 barrier/kk) ----------------
// grid 256 = 2b x 64 rows x 2 col-halves (32 px). 512 thr = 8 waves.
// LDS: Vs | Ws0 | Ws1 (Kh aliases Ws1's first 35840 B; Kh dead after phase A).
#define SM_VS   0
#define SM_WS0  35840
#define SM_WS1  93184
#define SM_KHA  93184
#define SM_AL2  150528
#define SM_LROW 157584
#define SM_LCS  157712
#define SM_MHS  157840
__global__ __launch_bounds__(512, 1) void k_out(
    const ushort* __restrict__ QH, const ushort* __restrict__ KH,
    const ushort* __restrict__ VH, const ushort* __restrict__ Wtb,
    const float* __restrict__ Lp,
    const float* __restrict__ MXq, const float* __restrict__ MXk,
    const float* __restrict__ bout, float* __restrict__ out)
{
    __shared__ __align__(16) char smem[157856];
    char*  Vsb  = smem + SM_VS;
    char*  Khb  = smem + SM_KHA;
    float* Al2  = (float*)(smem + SM_AL2);
    float* Lrow = (float*)(smem + SM_LROW);
    float* LcS  = (float*)(smem + SM_LCS);

    int bid0 = blockIdx.x;
    int bid  = (bid0 & 7) * 32 + (bid0 >> 3);   // XCD swizzle (256 = 8 x 32)
    int b   = bid >> 7;
    int rem = bid & 127;
    int i   = rem >> 1;
    int j0  = (rem & 1) * 32;
    int n0  = (i << 6) + j0;
    int t   = threadIdx.x;
    int w    = t >> 6;
    int L    = t & 63;
    int lrow = L & 15, lk = L >> 4;

    float bse = -mh_reduce(MXq, MXk, b, t, (float*)(smem + SM_MHS)) * LOG2E;
    float e0  = exp2f(bse);

    // T14 state for Ws staging
    bf16x8 wreg[7];
    #define ISSUE_WS(kk) {                                                          \
        _Pragma("unroll")                                                           \
        for (int s = 0; s < 7; ++s) {                                               \
            int g = t + s * 512;                                                    \
            int c8 = g & 7, och = (g >> 3) & 63, ll = g >> 9;                       \
            wreg[s] = *(const bf16x8*)(Wtb + ((size_t)(och * NTAP + (kk) * 7 + ll)) * 64 + c8 * 8); \
        } }
    #define WRITE_WS(dstb) {                                                        \
        _Pragma("unroll")                                                           \
        for (int s = 0; s < 7; ++s) {                                               \
            int g = t + s * 512;                                                    \
            int c8 = g & 7, och = (g >> 3) & 63, ll = g >> 9;                       \
            *(bf16x8*)((dstb) + ll * 8192 + och * 128 +                             \
                       ((c8 * 16) ^ ((och & 7) << 4))) = wreg[s];                   \
        } }

    // ---- stage V + K halos; Ws slice 0 -> Ws0 early (hides under phase A) ----
    for (int g = t; g < 2 * 7 * 38 * 8; g += 512) {
        int which = g >= 7 * 38 * 8;
        int gg = which ? g - 7 * 38 * 8 : g;
        int kk = gg / 304;
        int r2 = gg - kk * 304;
        int u  = r2 >> 3, c8 = r2 & 7;
        int vr = iclamp(i + kk - 3);
        int vc = iclamp(j0 - 3 + u);
        const ushort* src = which ? KH : VH;
        char* dst = which ? Khb : Vsb;
        bf16x8 val = *(const bf16x8*)(src + ((size_t)((b << 12) + (vr << 6) + vc)) * 64 + c8 * 8);
        *(bf16x8*)(dst + kk * 5120 + u * 128 + ((c8 * 16) ^ ((u & 7) << 4))) = val;
    }
    ISSUE_WS(0);
    WRITE_WS(smem + SM_WS0);
    if (t < 32) {
        int n = n0 + t;
        float s = 0.f;
        #pragma unroll
        for (int ks = 0; ks < 8; ++ks)
            s += Lp[((size_t)(ks * 2 + b) << 12) + n];
        Lrow[t] = s;
    }
    __syncthreads();

    // ---- phase A: local dots from LDS K-halo (32 px x 16 thr) ----
    {
        int p = t >> 4, u = t & 15;
        int n = n0 + p;
        int pj = n & 63;
        const ushort* qr = QH + ((size_t)(b << 12) + n) * 64;
        bf16x8 qv[8];
        #pragma unroll
        for (int c8 = 0; c8 < 8; ++c8) qv[c8] = *(const bf16x8*)(qr + c8 * 8);

        int nt = (u == 0) ? 4 : 3;
        float d[4] = {0.f, 0.f, 0.f, 0.f};
        int srcs[4];
        const char* kbp[4];
        int swzs[4];
        #pragma unroll
        for (int m = 0; m < 4; ++m) {
            int tap = (m == 3) ? 48 : (u + 16 * m);
            int kk = tap / 7, ll = tap - kk * 7;
            srcs[m] = (iclamp(i + kk - 3) << 6) + iclamp(pj + ll - 3);
            int uu = p + ll;
            kbp[m]  = Khb + kk * 5120 + uu * 128;
            swzs[m] = (uu & 7) << 4;
        }
        #pragma unroll
        for (int c8 = 0; c8 < 8; ++c8) {
            bf16x8 kv0 = *(const bf16x8*)(kbp[0] + ((c8 * 16) ^ swzs[0]));
            bf16x8 kv1 = *(const bf16x8*)(kbp[1] + ((c8 * 16) ^ swzs[1]));
            bf16x8 kv2 = *(const bf16x8*)(kbp[2] + ((c8 * 16) ^ swzs[2]));
            #pragma unroll
            for (int e = 0; e < 8; ++e) {
                float q = b2f((ushort)qv[c8][e]);
                d[0] = fmaf(q, b2f((ushort)kv0[e]), d[0]);
                d[1] = fmaf(q, b2f((ushort)kv1[e]), d[1]);
                d[2] = fmaf(q, b2f((ushort)kv2[e]), d[2]);
            }
        }
        if (nt == 4) {
            #pragma unroll
            for (int c8 = 0; c8 < 8; ++c8) {
                bf16x8 kv3 = *(const bf16x8*)(kbp[3] + ((c8 * 16) ^ swzs[3]));
                #pragma unroll
                for (int e = 0; e < 8; ++e)
                    d[3] = fmaf(b2f((ushort)qv[c8][e]), b2f((ushort)kv3[e]), d[3]);
            }
        }
        if (u == 8)                       // tap 24 = center (src == n always)
            LcS[p] = Lrow[p] - exp2f(fmaf(d[1], S2, bse)) + e0;
        __syncthreads();
        float rLc = 1.0f / LcS[p];
        for (int m = 0; m < nt; ++m) {
            int tap = (m == 3) ? 48 : (u + 16 * m);
            float A = (srcs[m] == n) ? (e0 * rLc)
                                     : (exp2f(fmaf(d[m], S2, bse)) * rLc);
            Al2[tap * 36 + p] = A;
        }
    }
    __syncthreads();                     // Al2 + Ws0 ready; Kh reads done

    // ---- phase B: per-tap MFMA, scale-after; double-buffered Ws, 1 barrier/kk ----
    int q16 = (w >> 2) << 4;
    int o16 = (w & 3) << 4;
    int oA  = o16 + lrow;
    int wswz = (oA & 7) << 4;
    f32x4 acc0 = {0.f, 0.f, 0.f, 0.f};

    for (int kk = 0; kk < 7; ++kk) {
        if (kk + 1 < 7) ISSUE_WS(kk + 1);
        const char* vrow = Vsb + kk * 5120;
        const char* wsb  = smem + ((kk & 1) ? SM_WS1 : SM_WS0);
        __builtin_amdgcn_s_setprio(1);
        #pragma unroll
        for (int ll = 0; ll < 7; ++ll) {
            int kl = kk * 7 + ll;
            int u = q16 + lrow + ll;
            const char* vb = vrow + u * 128;
            int swz = (u & 7) << 4;
            bf16x8 v0 = *(const bf16x8*)(vb + ((lk * 16) ^ swz));
            bf16x8 v1 = *(const bf16x8*)(vb + ((64 + lk * 16) ^ swz));
            float4 av = *(const float4*)(&Al2[kl * 36 + q16 + lk * 4]);
            const char* wb = wsb + ll * 8192 + oA * 128;
            bf16x8 b00 = *(const bf16x8*)(wb + ((lk * 16) ^ wswz));
            bf16x8 b01 = *(const bf16x8*)(wb + (((4 + lk) * 16) ^ wswz));
            f32x4 z = {0.f, 0.f, 0.f, 0.f};
            z = __builtin_amdgcn_mfma_f32_16x16x32_bf16(v0, b00, z, 0, 0, 0);
            z = __builtin_amdgcn_mfma_f32_16x16x32_bf16(v1, b01, z, 0, 0, 0);
            acc0[0] = fmaf(av.x, z[0], acc0[0]);
            acc0[1] = fmaf(av.y, z[1], acc0[1]);
            acc0[2] = fmaf(av.z, z[2], acc0[2]);
            acc0[3] = fmaf(av.w, z[3], acc0[3]);
        }
        __builtin_amdgcn_s_setprio(0);
        if (kk + 1 < 7) WRITE_WS(smem + (((kk + 1) & 1) ? SM_WS1 : SM_WS0));
        __syncthreads();                 // write(kk)->read(kk+1) AND read(kk)->write(kk+1)
    }

    int o = oA;
    int nbase = n0 + q16 + lk * 4;
    float bb = bout[o];
    float4 v = make_float4(fmaxf(acc0[0] + bb, 0.f), fmaxf(acc0[1] + bb, 0.f),
                           fmaxf(acc0[2] + bb, 0.f), fmaxf(acc0[3] + bb, 0.f));
    *(float4*)(out + (((size_t)(b * 64 + o)) << 12) + nbase) = v;
}

// ---------------- launch ----------------
extern "C" void kernel_launch(void* const* d_in, const int* in_sizes, int n_in,
                              void* d_out, int out_size, void* d_ws, size_t ws_size,
                              hipStream_t stream) {
    const float* x    = (const float*)d_in[0];
    const float* Wq   = (const float*)d_in[1];
    const float* bq   = (const float*)d_in[2];
    const float* Wk   = (const float*)d_in[3];
    const float* bk   = (const float*)d_in[4];
    const float* Wv   = (const float*)d_in[5];
    const float* bv   = (const float*)d_in[6];
    const float* Wp   = (const float*)d_in[7];
    const float* bp   = (const float*)d_in[8];
    const float* Wout = (const float*)d_in[9];
    const float* bout = (const float*)d_in[10];
    float* out = (float*)d_out;

    char* ws = (char*)d_ws;
    ushort* Wtb = (ushort*)(ws + WTB_OFF);
    ushort* QKV = (ushort*)(ws + QH_OFF);
    float*  Lp  = (float*)(ws + LP_OFF);
    float*  MXq = (float*)(ws + MXQ_OFF);
    float*  MXk = (float*)(ws + MXK_OFF);

    ushort* QH = QKV;
    ushort* KH = QKV + 524288;
    ushort* VH = QKV + 1048576;

    hipLaunchKernelGGL(k_qkv,   dim3(256), dim3(512), 0, stream,
                       x, Wq, Wk, Wv, bq, bk, bv, Wp, bp, QKV, MXq, MXk);
    hipLaunchKernelGGL(k_stats, dim3(512), dim3(512), 0, stream,
                       Wout, Wtb, QH, KH, MXq, MXk, Lp);
    hipLaunchKernelGGL(k_out,   dim3(256), dim3(512), 0, stream,
                       QH, KH, VH, Wtb, Lp, MXq, MXk, bout, out);
}